// Round 1
// baseline (370.436 us; speedup 1.0000x reference)
//
#include <hip/hip_runtime.h>

typedef unsigned short u16;
typedef __bf16 bf16x8 __attribute__((ext_vector_type(8)));
typedef float f32x4 __attribute__((ext_vector_type(4)));

#define NHEAD 12
#define LQ 1024
#define HDIM 64
#define DIMM 768

__device__ __forceinline__ u16 f2b(float f) {
  unsigned u = __float_as_uint(f);
  u += 0x7fffu + ((u >> 16) & 1u);   // RNE; inputs are finite
  return (u16)(u >> 16);
}
__device__ __forceinline__ float b2f(u16 v) {
  return __uint_as_float(((unsigned)v) << 16);
}
__device__ __forceinline__ void async16(const void* g, void* l) {
  __builtin_amdgcn_global_load_lds(
      (const __attribute__((address_space(1))) void*)g,
      (__attribute__((address_space(3))) void*)l, 16, 0, 0);
}

// ---------------- f32 -> bf16 convert ----------------
__global__ __launch_bounds__(256) void cvt_kernel(const float* __restrict__ in,
                                                  u16* __restrict__ out, int n4) {
  int i = blockIdx.x * 256 + threadIdx.x;
  if (i >= n4) return;
  const float4 v = reinterpret_cast<const float4*>(in)[i];
  ushort4 o;
  o.x = f2b(v.x); o.y = f2b(v.y); o.z = f2b(v.z); o.w = f2b(v.w);
  reinterpret_cast<ushort4*>(out)[i] = o;
}

// ---------------- QKV GEMM: C = A(8192x768) * Bt(2304x768)^T + bias ----------------
// scatter epilogue -> q[bh][l][d], k[bh][l][d], vT[bh][d][l]  (bf16)
__global__ __launch_bounds__(256) void gemm_qkv(const u16* __restrict__ A,
                                                const u16* __restrict__ Bt,
                                                const float* __restrict__ bias,
                                                u16* __restrict__ qb,
                                                u16* __restrict__ kb,
                                                u16* __restrict__ vtb) {
  __shared__ u16 la[128 * 32];
  __shared__ u16 lb[128 * 32];
  const int K = DIMM;
  int t = threadIdx.x;
  int lane = t & 63, wv = t >> 6;
  int l15 = lane & 15, l4 = lane >> 4;
  int bm = blockIdx.x / 18, bn = blockIdx.x % 18;
  int m0 = bm * 128, n0 = bn * 128;
  int wm = (wv >> 1) * 64, wn = (wv & 1) * 64;

  f32x4 acc[4][4];
  #pragma unroll
  for (int i = 0; i < 4; ++i)
    #pragma unroll
    for (int j = 0; j < 4; ++j) acc[i][j] = {0.f, 0.f, 0.f, 0.f};

  for (int k0 = 0; k0 < K; k0 += 32) {
    __syncthreads();
    #pragma unroll
    for (int i = 0; i < 2; ++i) {
      int c = i * 256 + t;
      int row = c >> 2, co = c & 3;
      async16(A + (m0 + row) * K + k0 + co * 8, (char*)la + c * 16);
      async16(Bt + (n0 + row) * K + k0 + co * 8, (char*)lb + c * 16);
    }
    __syncthreads();
    bf16x8 af[4], bfr[4];
    #pragma unroll
    for (int mi = 0; mi < 4; ++mi)
      af[mi] = *reinterpret_cast<const bf16x8*>(&la[(wm + mi * 16 + l15) * 32 + l4 * 8]);
    #pragma unroll
    for (int nj = 0; nj < 4; ++nj)
      bfr[nj] = *reinterpret_cast<const bf16x8*>(&lb[(wn + nj * 16 + l15) * 32 + l4 * 8]);
    #pragma unroll
    for (int mi = 0; mi < 4; ++mi)
      #pragma unroll
      for (int nj = 0; nj < 4; ++nj)
        acc[mi][nj] = __builtin_amdgcn_mfma_f32_16x16x32_bf16(af[mi], bfr[nj], acc[mi][nj], 0, 0, 0);
  }

  int part = (n0 >> 7) / 6;  // 0:q 1:k 2:v (768 = 6 tiles of 128)
  #pragma unroll
  for (int nj = 0; nj < 4; ++nj) {
    int n = n0 + wn + nj * 16 + l15;
    float bv = bias[n];
    int d = n & 63;
    int head = (n >> 6) % NHEAD;
    #pragma unroll
    for (int mi = 0; mi < 4; ++mi) {
      #pragma unroll
      for (int r = 0; r < 4; ++r) {
        int m = m0 + wm + mi * 16 + l4 * 4 + r;
        int b = m >> 10, li = m & 1023;
        int bh = b * NHEAD + head;
        u16 o = f2b(acc[mi][nj][r] + bv);
        if (part == 0)      qb[(bh * LQ + li) * HDIM + d] = o;
        else if (part == 1) kb[(bh * LQ + li) * HDIM + d] = o;
        else                vtb[(bh * HDIM + d) * LQ + li] = o;
      }
    }
  }
}

// ---------------- rel-pos bias vectors: Rh[bh][l][32], Rw[bh][l][32] (f32) ----------------
__global__ __launch_bounds__(256) void bias_kernel(const u16* __restrict__ qb,
                                                   const float* __restrict__ rph,
                                                   const float* __restrict__ rpw,
                                                   float* __restrict__ Rh,
                                                   float* __restrict__ Rw) {
  __shared__ float lq[4][64];
  int w = threadIdx.x >> 6, l = threadIdx.x & 63;
  int bh = blockIdx.x >> 8;               // 256 groups of 4 rows
  int lrow = ((blockIdx.x & 255) << 2) + w;
  lq[w][l] = b2f(qb[(bh * LQ + lrow) * HDIM + l]);
  __syncthreads();
  int h = lrow >> 5, ww = lrow & 31;
  int j = l & 31;
  const float* rel = (l < 32) ? (rph + (h - j + 31) * HDIM)
                              : (rpw + (ww - j + 31) * HDIM);
  float* outp = (l < 32) ? Rh : Rw;
  float acc = 0.f;
  #pragma unroll
  for (int d = 0; d < 64; ++d) acc += lq[w][d] * rel[d];
  outp[(bh * LQ + lrow) * 32 + j] = acc;
}

// ---------------- flash attention with decomposed rel-pos bias ----------------
// block: 4 waves, QBLK=64 (wave -> 16 rows), KV chunks of 64
__global__ __launch_bounds__(256) void attn_kernel(const u16* __restrict__ qb,
                                                   const u16* __restrict__ kb,
                                                   const u16* __restrict__ vtb,
                                                   const float* __restrict__ Rh,
                                                   const float* __restrict__ Rw,
                                                   u16* __restrict__ ao) {
  __shared__ u16 lds_k[64 * 64];       // [key][d], source-swizzled
  __shared__ u16 lds_v[64 * 64];       // [d][key], source-swizzled
  __shared__ float lds_rh[64 * 32];
  __shared__ float lds_rw[64 * 32];
  __shared__ u16 lds_p[4][16 * 72];    // per-wave P tile, padded row 72

  int bid = blockIdx.x;
  int bh = bid >> 4;
  int q0 = (bid & 15) * 64;
  int t = threadIdx.x;
  int wv = t >> 6, lane = t & 63;
  int l15 = lane & 15, l4 = lane >> 4;

  // stage Rh/Rw for this q-tile (contiguous 8KB each)
  {
    const float* sh = Rh + (bh * LQ + q0) * 32;
    const float* sw = Rw + (bh * LQ + q0) * 32;
    #pragma unroll
    for (int i = 0; i < 2; ++i) {
      int c = i * 256 + t;
      async16(sh + c * 4, (char*)lds_rh + c * 16);
      async16(sw + c * 4, (char*)lds_rw + c * 16);
    }
  }

  // Q fragments (2 x K=32) straight from global
  bf16x8 qf[2];
  {
    const u16* qsrc = qb + (bh * LQ + q0 + wv * 16 + l15) * HDIM + l4 * 8;
    qf[0] = *reinterpret_cast<const bf16x8*>(qsrc);
    qf[1] = *reinterpret_cast<const bf16x8*>(qsrc + 32);
  }

  float m_run[4], l_run[4];
  f32x4 acc_o[4];
  #pragma unroll
  for (int r = 0; r < 4; ++r) { m_run[r] = -1e30f; l_run[r] = 0.f; }
  #pragma unroll
  for (int dj = 0; dj < 4; ++dj) acc_o[dj] = {0.f, 0.f, 0.f, 0.f};

  int rowb = wv * 16 + l4 * 4;
  u16* pl = &lds_p[wv][0];

  for (int kv0 = 0; kv0 < LQ; kv0 += 64) {
    __syncthreads();   // previous chunk's LDS reads done (also drains Rh/Rw copy)
    {
      const u16* ks = kb + (bh * LQ + kv0) * HDIM;
      const u16* vs = vtb + bh * HDIM * LQ + kv0;
      #pragma unroll
      for (int i = 0; i < 2; ++i) {
        int c = i * 256 + t;
        int row = c >> 3, co = c & 7;
        int g = co ^ (row & 7);          // source swizzle; LDS stays linear
        async16(ks + row * HDIM + g * 8, (char*)lds_k + c * 16);
        async16(vs + row * LQ + g * 8, (char*)lds_v + c * 16);
      }
    }
    __syncthreads();

    // QK^T
    f32x4 sc[4];
    #pragma unroll
    for (int nj = 0; nj < 4; ++nj) {
      int key = nj * 16 + l15;
      f32x4 a = {0.f, 0.f, 0.f, 0.f};
      #pragma unroll
      for (int ks2 = 0; ks2 < 2; ++ks2) {
        int co = (ks2 * 4 + l4) ^ (key & 7);
        bf16x8 kf = *reinterpret_cast<const bf16x8*>(&lds_k[key * 64 + co * 8]);
        a = __builtin_amdgcn_mfma_f32_16x16x32_bf16(qf[ks2], kf, a, 0, 0, 0);
      }
      sc[nj] = a;
    }

    // scores + bias, online softmax
    float p[4][4];
    float cmax[4] = {-1e30f, -1e30f, -1e30f, -1e30f};
    #pragma unroll
    for (int nj = 0; nj < 4; ++nj) {
      int kk = kv0 + nj * 16 + l15;
      int k1 = kk >> 5, k2 = kk & 31;
      #pragma unroll
      for (int r = 0; r < 4; ++r) {
        float s = sc[nj][r] * 0.125f + lds_rh[(rowb + r) * 32 + k1]
                                     + lds_rw[(rowb + r) * 32 + k2];
        p[nj][r] = s;
        cmax[r] = fmaxf(cmax[r], s);
      }
    }
    #pragma unroll
    for (int r = 0; r < 4; ++r) {
      cmax[r] = fmaxf(cmax[r], __shfl_xor(cmax[r], 1));
      cmax[r] = fmaxf(cmax[r], __shfl_xor(cmax[r], 2));
      cmax[r] = fmaxf(cmax[r], __shfl_xor(cmax[r], 4));
      cmax[r] = fmaxf(cmax[r], __shfl_xor(cmax[r], 8));
    }
    float scl[4], psum[4];
    #pragma unroll
    for (int r = 0; r < 4; ++r) {
      float mn = fmaxf(m_run[r], cmax[r]);
      scl[r] = __expf(m_run[r] - mn);
      m_run[r] = mn;
      float s = 0.f;
      #pragma unroll
      for (int nj = 0; nj < 4; ++nj) {
        p[nj][r] = __expf(p[nj][r] - mn);
        s += p[nj][r];
      }
      psum[r] = s;
    }
    #pragma unroll
    for (int r = 0; r < 4; ++r) {
      psum[r] += __shfl_xor(psum[r], 1);
      psum[r] += __shfl_xor(psum[r], 2);
      psum[r] += __shfl_xor(psum[r], 4);
      psum[r] += __shfl_xor(psum[r], 8);
      l_run[r] = l_run[r] * scl[r] + psum[r];
    }
    #pragma unroll
    for (int dj = 0; dj < 4; ++dj)
      #pragma unroll
      for (int r = 0; r < 4; ++r) acc_o[dj][r] *= scl[r];

    // P -> LDS (bf16), re-read as A-fragments (wave-private; DS is in-order per wave)
    #pragma unroll
    for (int nj = 0; nj < 4; ++nj)
      #pragma unroll
      for (int r = 0; r < 4; ++r)
        pl[(l4 * 4 + r) * 72 + nj * 16 + l15] = f2b(p[nj][r]);

    bf16x8 pf[2];
    pf[0] = *reinterpret_cast<const bf16x8*>(&pl[l15 * 72 + l4 * 8]);
    pf[1] = *reinterpret_cast<const bf16x8*>(&pl[l15 * 72 + 32 + l4 * 8]);

    // PV
    #pragma unroll
    for (int dj = 0; dj < 4; ++dj) {
      int d = dj * 16 + l15;
      #pragma unroll
      for (int ks2 = 0; ks2 < 2; ++ks2) {
        int co = (ks2 * 4 + l4) ^ (d & 7);
        bf16x8 vf = *reinterpret_cast<const bf16x8*>(&lds_v[d * 64 + co * 8]);
        acc_o[dj] = __builtin_amdgcn_mfma_f32_16x16x32_bf16(pf[ks2], vf, acc_o[dj], 0, 0, 0);
      }
    }
  }

  // epilogue: normalize, write ao[b][l][head*64+d] bf16
  int b = bh / NHEAD, head = bh % NHEAD;
  #pragma unroll
  for (int r = 0; r < 4; ++r) {
    int qrow = q0 + wv * 16 + l4 * 4 + r;
    float inv = 1.f / l_run[r];
    #pragma unroll
    for (int dj = 0; dj < 4; ++dj) {
      int d = dj * 16 + l15;
      ao[(b * LQ + qrow) * DIMM + head * HDIM + d] = f2b(acc_o[dj][r] * inv);
    }
  }
}

// ---------------- proj GEMM: out = A(8192x768) * Bt(768x768)^T + bias (f32 out) ----------------
__global__ __launch_bounds__(256) void gemm_proj(const u16* __restrict__ A,
                                                 const u16* __restrict__ Bt,
                                                 const float* __restrict__ bias,
                                                 float* __restrict__ out) {
  __shared__ u16 la[128 * 32];
  __shared__ u16 lb[128 * 32];
  const int K = DIMM;
  int t = threadIdx.x;
  int lane = t & 63, wv = t >> 6;
  int l15 = lane & 15, l4 = lane >> 4;
  int bm = blockIdx.x / 6, bn = blockIdx.x % 6;
  int m0 = bm * 128, n0 = bn * 128;
  int wm = (wv >> 1) * 64, wn = (wv & 1) * 64;

  f32x4 acc[4][4];
  #pragma unroll
  for (int i = 0; i < 4; ++i)
    #pragma unroll
    for (int j = 0; j < 4; ++j) acc[i][j] = {0.f, 0.f, 0.f, 0.f};

  for (int k0 = 0; k0 < K; k0 += 32) {
    __syncthreads();
    #pragma unroll
    for (int i = 0; i < 2; ++i) {
      int c = i * 256 + t;
      int row = c >> 2, co = c & 3;
      async16(A + (m0 + row) * K + k0 + co * 8, (char*)la + c * 16);
      async16(Bt + (n0 + row) * K + k0 + co * 8, (char*)lb + c * 16);
    }
    __syncthreads();
    bf16x8 af[4], bfr[4];
    #pragma unroll
    for (int mi = 0; mi < 4; ++mi)
      af[mi] = *reinterpret_cast<const bf16x8*>(&la[(wm + mi * 16 + l15) * 32 + l4 * 8]);
    #pragma unroll
    for (int nj = 0; nj < 4; ++nj)
      bfr[nj] = *reinterpret_cast<const bf16x8*>(&lb[(wn + nj * 16 + l15) * 32 + l4 * 8]);
    #pragma unroll
    for (int mi = 0; mi < 4; ++mi)
      #pragma unroll
      for (int nj = 0; nj < 4; ++nj)
        acc[mi][nj] = __builtin_amdgcn_mfma_f32_16x16x32_bf16(af[mi], bfr[nj], acc[mi][nj], 0, 0, 0);
  }

  #pragma unroll
  for (int nj = 0; nj < 4; ++nj) {
    int n = n0 + wn + nj * 16 + l15;
    float bv = bias[n];
    #pragma unroll
    for (int mi = 0; mi < 4; ++mi) {
      #pragma unroll
      for (int r = 0; r < 4; ++r) {
        int m = m0 + wm + mi * 16 + l4 * 4 + r;
        out[m * DIMM + n] = acc[mi][nj][r] + bv;
      }
    }
  }
}

extern "C" void kernel_launch(void* const* d_in, const int* in_sizes, int n_in,
                              void* d_out, int out_size, void* d_ws, size_t ws_size,
                              hipStream_t stream) {
  const float* x      = (const float*)d_in[0];
  const float* qkv_w  = (const float*)d_in[1];
  const float* qkv_b  = (const float*)d_in[2];
  const float* proj_w = (const float*)d_in[3];
  const float* proj_b = (const float*)d_in[4];
  const float* rph    = (const float*)d_in[5];
  const float* rpw    = (const float*)d_in[6];
  float* out = (float*)d_out;
  char* ws = (char*)d_ws;

  // workspace layout (total ~80.2 MB; ao aliases xb)
  u16*   xb     = (u16*)(ws + 0);          // 8192*768 bf16 (12.58 MB)
  u16*   wqkvb  = (u16*)(ws + 12582912);   // 2304*768
  u16*   wprojb = (u16*)(ws + 16121856);   // 768*768
  u16*   qb     = (u16*)(ws + 17301504);   // 96*1024*64
  u16*   kb     = (u16*)(ws + 29884416);
  u16*   vtb    = (u16*)(ws + 42467328);   // transposed V [bh][d][l]
  float* Rh     = (float*)(ws + 55050240); // 96*1024*32 f32
  float* Rw     = (float*)(ws + 67633152);
  u16*   ao     = xb;                      // reuse after QKV GEMM consumed xb

  cvt_kernel<<<6144, 256, 0, stream>>>(x, xb, 8192 * 768 / 4);
  cvt_kernel<<<1728, 256, 0, stream>>>(qkv_w, wqkvb, 2304 * 768 / 4);
  cvt_kernel<<<576, 256, 0, stream>>>(proj_w, wprojb, 768 * 768 / 4);

  gemm_qkv<<<64 * 18, 256, 0, stream>>>(xb, wqkvb, qkv_b, qb, kb, vtb);

  bias_kernel<<<96 * 256, 256, 0, stream>>>(qb, rph, rpw, Rh, Rw);

  attn_kernel<<<96 * 16, 256, 0, stream>>>(qb, kb, vtb, Rh, Rw, ao);

  gemm_proj<<<64 * 6, 256, 0, stream>>>(ao, wprojb, proj_b, out);
}

// Round 2
// 211.212 us; speedup vs baseline: 1.7539x; 1.7539x over previous
//
#include <hip/hip_runtime.h>

typedef unsigned short u16;
typedef __bf16 bf16x8 __attribute__((ext_vector_type(8)));
typedef float f32x4 __attribute__((ext_vector_type(4)));

#define NHEAD 12
#define LQ 1024
#define HDIM 64
#define DIMM 768

__device__ __forceinline__ u16 f2b(float f) {
  unsigned u = __float_as_uint(f);
  u += 0x7fffu + ((u >> 16) & 1u);   // RNE; inputs are finite
  return (u16)(u >> 16);
}
__device__ __forceinline__ float b2f(u16 v) {
  return __uint_as_float(((unsigned)v) << 16);
}
__device__ __forceinline__ void async16(const void* g, void* l) {
  __builtin_amdgcn_global_load_lds(
      (const __attribute__((address_space(1))) void*)g,
      (__attribute__((address_space(3))) void*)l, 16, 0, 0);
}

// ---------------- f32 -> bf16 convert ----------------
__global__ __launch_bounds__(256) void cvt_kernel(const float* __restrict__ in,
                                                  u16* __restrict__ out, int n4) {
  int i = blockIdx.x * 256 + threadIdx.x;
  if (i >= n4) return;
  const float4 v = reinterpret_cast<const float4*>(in)[i];
  ushort4 o;
  o.x = f2b(v.x); o.y = f2b(v.y); o.z = f2b(v.z); o.w = f2b(v.w);
  reinterpret_cast<ushort4*>(out)[i] = o;
}

// rel tables -> padded bf16 [64][64] (row 63 zero, never indexed)
__global__ __launch_bounds__(256) void cvt_rel(const float* __restrict__ rph,
                                               const float* __restrict__ rpw,
                                               u16* __restrict__ rphb,
                                               u16* __restrict__ rpwb) {
  int i = blockIdx.x * 256 + threadIdx.x;   // 0..8191
  int tab = i >> 12, idx = i & 4095;
  int m = idx >> 6, d = idx & 63;
  const float* src = tab ? rpw : rph;
  u16* dst = tab ? rpwb : rphb;
  dst[idx] = (m < 63) ? f2b(src[m * HDIM + d]) : (u16)0;
}

// ---------------- QKV GEMM: C = A(8192x768) * Bt(2304x768)^T + bias ----------------
// scatter epilogue -> q[bh][l][d], k[bh][l][d], vT[bh][d][l]  (bf16)
__global__ __launch_bounds__(256) void gemm_qkv(const u16* __restrict__ A,
                                                const u16* __restrict__ Bt,
                                                const float* __restrict__ bias,
                                                u16* __restrict__ qb,
                                                u16* __restrict__ kb,
                                                u16* __restrict__ vtb) {
  __shared__ u16 la[128 * 32];
  __shared__ u16 lb[128 * 32];
  const int K = DIMM;
  int t = threadIdx.x;
  int lane = t & 63, wv = t >> 6;
  int l15 = lane & 15, l4 = lane >> 4;
  int bm = blockIdx.x / 18, bn = blockIdx.x % 18;
  int m0 = bm * 128, n0 = bn * 128;
  int wm = (wv >> 1) * 64, wn = (wv & 1) * 64;

  f32x4 acc[4][4];
  #pragma unroll
  for (int i = 0; i < 4; ++i)
    #pragma unroll
    for (int j = 0; j < 4; ++j) acc[i][j] = {0.f, 0.f, 0.f, 0.f};

  for (int k0 = 0; k0 < K; k0 += 32) {
    __syncthreads();
    #pragma unroll
    for (int i = 0; i < 2; ++i) {
      int c = i * 256 + t;
      int row = c >> 2, co = c & 3;
      async16(A + (m0 + row) * K + k0 + co * 8, (char*)la + c * 16);
      async16(Bt + (n0 + row) * K + k0 + co * 8, (char*)lb + c * 16);
    }
    __syncthreads();
    bf16x8 af[4], bfr[4];
    #pragma unroll
    for (int mi = 0; mi < 4; ++mi)
      af[mi] = *reinterpret_cast<const bf16x8*>(&la[(wm + mi * 16 + l15) * 32 + l4 * 8]);
    #pragma unroll
    for (int nj = 0; nj < 4; ++nj)
      bfr[nj] = *reinterpret_cast<const bf16x8*>(&lb[(wn + nj * 16 + l15) * 32 + l4 * 8]);
    #pragma unroll
    for (int mi = 0; mi < 4; ++mi)
      #pragma unroll
      for (int nj = 0; nj < 4; ++nj)
        acc[mi][nj] = __builtin_amdgcn_mfma_f32_16x16x32_bf16(af[mi], bfr[nj], acc[mi][nj], 0, 0, 0);
  }

  int part = (n0 >> 7) / 6;  // 0:q 1:k 2:v (768 = 6 tiles of 128)
  #pragma unroll
  for (int nj = 0; nj < 4; ++nj) {
    int n = n0 + wn + nj * 16 + l15;
    float bv = bias[n];
    int d = n & 63;
    int head = (n >> 6) % NHEAD;
    #pragma unroll
    for (int mi = 0; mi < 4; ++mi) {
      #pragma unroll
      for (int r = 0; r < 4; ++r) {
        int m = m0 + wm + mi * 16 + l4 * 4 + r;
        int b = m >> 10, li = m & 1023;
        int bh = b * NHEAD + head;
        u16 o = f2b(acc[mi][nj][r] + bv);
        if (part == 0)      qb[(bh * LQ + li) * HDIM + d] = o;
        else if (part == 1) kb[(bh * LQ + li) * HDIM + d] = o;
        else                vtb[(bh * HDIM + d) * LQ + li] = o;
      }
    }
  }
}

// ---------------- flash attention with fused decomposed rel-pos bias ----------------
// block: 4 waves, QBLK=64 (wave -> 16 rows), KV chunks of 64
// bias fused via T-tables: Th[l][m] = q[l].rph[m]; score bias = Th[l][hq-k1+31] + Tw[l][wq-k2+31]
__global__ __launch_bounds__(256) void attn_kernel(const u16* __restrict__ qb,
                                                   const u16* __restrict__ kb,
                                                   const u16* __restrict__ vtb,
                                                   const u16* __restrict__ rphb,
                                                   const u16* __restrict__ rpwb,
                                                   u16* __restrict__ ao) {
  __shared__ u16 lds_k[64 * 64];       // [key][d], source-swizzled
  __shared__ u16 lds_v[64 * 64];       // [d][key], source-swizzled
  __shared__ u16 lds_th[64 * 72];      // T-tables, bf16, padded stride 72
  __shared__ u16 lds_tw[64 * 72];
  __shared__ u16 lds_p[4][16 * 72];    // per-wave P tile, padded row 72

  int bid = blockIdx.x;
  int bh = bid >> 4;
  int q0 = (bid & 15) * 64;
  int t = threadIdx.x;
  int wv = t >> 6, lane = t & 63;
  int l15 = lane & 15, l4 = lane >> 4;

  // Q fragments (2 x K=32) straight from global
  bf16x8 qf[2];
  {
    const u16* qsrc = qb + (bh * LQ + q0 + wv * 16 + l15) * HDIM + l4 * 8;
    qf[0] = *reinterpret_cast<const bf16x8*>(qsrc);
    qf[1] = *reinterpret_cast<const bf16x8*>(qsrc + 32);
  }

  // compute T-tables via MFMA: wave wv owns rows [wv*16, wv*16+16) (wave-private, no barrier)
  #pragma unroll
  for (int c = 0; c < 4; ++c) {
    f32x4 th = {0.f, 0.f, 0.f, 0.f}, tw = {0.f, 0.f, 0.f, 0.f};
    #pragma unroll
    for (int ks2 = 0; ks2 < 2; ++ks2) {
      bf16x8 bhf = *reinterpret_cast<const bf16x8*>(&rphb[(c * 16 + l15) * HDIM + ks2 * 32 + l4 * 8]);
      bf16x8 bwf = *reinterpret_cast<const bf16x8*>(&rpwb[(c * 16 + l15) * HDIM + ks2 * 32 + l4 * 8]);
      th = __builtin_amdgcn_mfma_f32_16x16x32_bf16(qf[ks2], bhf, th, 0, 0, 0);
      tw = __builtin_amdgcn_mfma_f32_16x16x32_bf16(qf[ks2], bwf, tw, 0, 0, 0);
    }
    #pragma unroll
    for (int r = 0; r < 4; ++r) {
      int row = wv * 16 + l4 * 4 + r;
      lds_th[row * 72 + c * 16 + l15] = f2b(th[r]);
      lds_tw[row * 72 + c * 16 + l15] = f2b(tw[r]);
    }
  }

  float m_run[4], l_run[4];
  f32x4 acc_o[4];
  #pragma unroll
  for (int r = 0; r < 4; ++r) { m_run[r] = -1e30f; l_run[r] = 0.f; }
  #pragma unroll
  for (int dj = 0; dj < 4; ++dj) acc_o[dj] = {0.f, 0.f, 0.f, 0.f};

  int rowb = wv * 16 + l4 * 4;
  u16* pl = &lds_p[wv][0];
  // per-row hoisted gather bases
  int thbase[4], twbase[4];
  #pragma unroll
  for (int r = 0; r < 4; ++r) {
    int row = rowb + r;
    thbase[r] = row * 72 + ((q0 + row) >> 5) + 31;   // minus kv5 per chunk, minus (nj>>1)
    twbase[r] = row * 72 + (row & 31) + 31;          // minus (nj&1)*16 + l15
  }

  for (int kv0 = 0; kv0 < LQ; kv0 += 64) {
    __syncthreads();   // previous chunk's LDS reads done
    {
      const u16* ks = kb + (bh * LQ + kv0) * HDIM;
      const u16* vs = vtb + bh * HDIM * LQ + kv0;
      #pragma unroll
      for (int i = 0; i < 2; ++i) {
        int c = i * 256 + t;
        int row = c >> 3, co = c & 7;
        int g = co ^ (row & 7);          // source swizzle; LDS stays linear
        async16(ks + row * HDIM + g * 8, (char*)lds_k + c * 16);
        async16(vs + row * LQ + g * 8, (char*)lds_v + c * 16);
      }
    }
    __syncthreads();

    // QK^T
    f32x4 sc[4];
    #pragma unroll
    for (int nj = 0; nj < 4; ++nj) {
      int key = nj * 16 + l15;
      f32x4 a = {0.f, 0.f, 0.f, 0.f};
      #pragma unroll
      for (int ks2 = 0; ks2 < 2; ++ks2) {
        int co = (ks2 * 4 + l4) ^ (key & 7);
        bf16x8 kf = *reinterpret_cast<const bf16x8*>(&lds_k[key * 64 + co * 8]);
        a = __builtin_amdgcn_mfma_f32_16x16x32_bf16(qf[ks2], kf, a, 0, 0, 0);
      }
      sc[nj] = a;
    }

    // Th term: constant across l15 within an nj pair -> 2 scalar LDS reads per row
    int kv5 = kv0 >> 5;
    float thv[4][2];
    #pragma unroll
    for (int r = 0; r < 4; ++r) {
      int b0 = thbase[r] - kv5;
      thv[r][0] = b2f(lds_th[b0]);
      thv[r][1] = b2f(lds_th[b0 - 1]);
    }

    // scores + bias, online softmax
    float p[4][4];
    float cmax[4] = {-1e30f, -1e30f, -1e30f, -1e30f};
    #pragma unroll
    for (int nj = 0; nj < 4; ++nj) {
      int koff = (nj & 1) * 16 + l15;
      #pragma unroll
      for (int r = 0; r < 4; ++r) {
        float s = fmaf(sc[nj][r], 0.125f, thv[r][nj >> 1])
                + b2f(lds_tw[twbase[r] - koff]);
        p[nj][r] = s;
        cmax[r] = fmaxf(cmax[r], s);
      }
    }
    #pragma unroll
    for (int r = 0; r < 4; ++r) {
      cmax[r] = fmaxf(cmax[r], __shfl_xor(cmax[r], 1));
      cmax[r] = fmaxf(cmax[r], __shfl_xor(cmax[r], 2));
      cmax[r] = fmaxf(cmax[r], __shfl_xor(cmax[r], 4));
      cmax[r] = fmaxf(cmax[r], __shfl_xor(cmax[r], 8));
    }
    float scl[4], psum[4];
    #pragma unroll
    for (int r = 0; r < 4; ++r) {
      float mn = fmaxf(m_run[r], cmax[r]);
      scl[r] = __expf(m_run[r] - mn);
      m_run[r] = mn;
      float s = 0.f;
      #pragma unroll
      for (int nj = 0; nj < 4; ++nj) {
        p[nj][r] = __expf(p[nj][r] - mn);
        s += p[nj][r];
      }
      psum[r] = s;
    }
    #pragma unroll
    for (int r = 0; r < 4; ++r) {
      psum[r] += __shfl_xor(psum[r], 1);
      psum[r] += __shfl_xor(psum[r], 2);
      psum[r] += __shfl_xor(psum[r], 4);
      psum[r] += __shfl_xor(psum[r], 8);
      l_run[r] = l_run[r] * scl[r] + psum[r];
    }
    #pragma unroll
    for (int dj = 0; dj < 4; ++dj)
      #pragma unroll
      for (int r = 0; r < 4; ++r) acc_o[dj][r] *= scl[r];

    // P -> LDS (bf16), re-read as A-fragments (wave-private; DS is in-order per wave)
    #pragma unroll
    for (int nj = 0; nj < 4; ++nj)
      #pragma unroll
      for (int r = 0; r < 4; ++r)
        pl[(l4 * 4 + r) * 72 + nj * 16 + l15] = f2b(p[nj][r]);

    bf16x8 pf[2];
    pf[0] = *reinterpret_cast<const bf16x8*>(&pl[l15 * 72 + l4 * 8]);
    pf[1] = *reinterpret_cast<const bf16x8*>(&pl[l15 * 72 + 32 + l4 * 8]);

    // PV
    #pragma unroll
    for (int dj = 0; dj < 4; ++dj) {
      int d = dj * 16 + l15;
      #pragma unroll
      for (int ks2 = 0; ks2 < 2; ++ks2) {
        int co = (ks2 * 4 + l4) ^ (d & 7);
        bf16x8 vf = *reinterpret_cast<const bf16x8*>(&lds_v[d * 64 + co * 8]);
        acc_o[dj] = __builtin_amdgcn_mfma_f32_16x16x32_bf16(pf[ks2], vf, acc_o[dj], 0, 0, 0);
      }
    }
  }

  // epilogue: normalize, write ao[b][l][head*64+d] bf16
  int b = bh / NHEAD, head = bh % NHEAD;
  #pragma unroll
  for (int r = 0; r < 4; ++r) {
    int qrow = q0 + wv * 16 + l4 * 4 + r;
    float inv = 1.f / l_run[r];
    #pragma unroll
    for (int dj = 0; dj < 4; ++dj) {
      int d = dj * 16 + l15;
      ao[(b * LQ + qrow) * DIMM + head * HDIM + d] = f2b(acc_o[dj][r] * inv);
    }
  }
}

// ---------------- proj GEMM: out = A(8192x768) * Bt(768x768)^T + bias (f32 out) ----------------
__global__ __launch_bounds__(256) void gemm_proj(const u16* __restrict__ A,
                                                 const u16* __restrict__ Bt,
                                                 const float* __restrict__ bias,
                                                 float* __restrict__ out) {
  __shared__ u16 la[128 * 32];
  __shared__ u16 lb[128 * 32];
  const int K = DIMM;
  int t = threadIdx.x;
  int lane = t & 63, wv = t >> 6;
  int l15 = lane & 15, l4 = lane >> 4;
  int bm = blockIdx.x / 6, bn = blockIdx.x % 6;
  int m0 = bm * 128, n0 = bn * 128;
  int wm = (wv >> 1) * 64, wn = (wv & 1) * 64;

  f32x4 acc[4][4];
  #pragma unroll
  for (int i = 0; i < 4; ++i)
    #pragma unroll
    for (int j = 0; j < 4; ++j) acc[i][j] = {0.f, 0.f, 0.f, 0.f};

  for (int k0 = 0; k0 < K; k0 += 32) {
    __syncthreads();
    #pragma unroll
    for (int i = 0; i < 2; ++i) {
      int c = i * 256 + t;
      int row = c >> 2, co = c & 3;
      async16(A + (m0 + row) * K + k0 + co * 8, (char*)la + c * 16);
      async16(Bt + (n0 + row) * K + k0 + co * 8, (char*)lb + c * 16);
    }
    __syncthreads();
    bf16x8 af[4], bfr[4];
    #pragma unroll
    for (int mi = 0; mi < 4; ++mi)
      af[mi] = *reinterpret_cast<const bf16x8*>(&la[(wm + mi * 16 + l15) * 32 + l4 * 8]);
    #pragma unroll
    for (int nj = 0; nj < 4; ++nj)
      bfr[nj] = *reinterpret_cast<const bf16x8*>(&lb[(wn + nj * 16 + l15) * 32 + l4 * 8]);
    #pragma unroll
    for (int mi = 0; mi < 4; ++mi)
      #pragma unroll
      for (int nj = 0; nj < 4; ++nj)
        acc[mi][nj] = __builtin_amdgcn_mfma_f32_16x16x32_bf16(af[mi], bfr[nj], acc[mi][nj], 0, 0, 0);
  }

  #pragma unroll
  for (int nj = 0; nj < 4; ++nj) {
    int n = n0 + wn + nj * 16 + l15;
    float bv = bias[n];
    #pragma unroll
    for (int mi = 0; mi < 4; ++mi) {
      #pragma unroll
      for (int r = 0; r < 4; ++r) {
        int m = m0 + wm + mi * 16 + l4 * 4 + r;
        out[m * DIMM + n] = acc[mi][nj][r] + bv;
      }
    }
  }
}

extern "C" void kernel_launch(void* const* d_in, const int* in_sizes, int n_in,
                              void* d_out, int out_size, void* d_ws, size_t ws_size,
                              hipStream_t stream) {
  const float* x      = (const float*)d_in[0];
  const float* qkv_w  = (const float*)d_in[1];
  const float* qkv_b  = (const float*)d_in[2];
  const float* proj_w = (const float*)d_in[3];
  const float* proj_b = (const float*)d_in[4];
  const float* rph    = (const float*)d_in[5];
  const float* rpw    = (const float*)d_in[6];
  float* out = (float*)d_out;
  char* ws = (char*)d_ws;

  // workspace layout (ao aliases xb)
  u16*   xb     = (u16*)(ws + 0);          // 8192*768 bf16 (12.58 MB)
  u16*   wqkvb  = (u16*)(ws + 12582912);   // 2304*768
  u16*   wprojb = (u16*)(ws + 16121856);   // 768*768
  u16*   qb     = (u16*)(ws + 17301504);   // 96*1024*64
  u16*   kb     = (u16*)(ws + 29884416);
  u16*   vtb    = (u16*)(ws + 42467328);   // transposed V [bh][d][l]
  u16*   rphb   = (u16*)(ws + 55050240);   // padded bf16 [64][64]
  u16*   rpwb   = (u16*)(ws + 55058432);
  u16*   ao     = xb;                      // reuse after QKV GEMM consumed xb

  cvt_kernel<<<6144, 256, 0, stream>>>(x, xb, 8192 * 768 / 4);
  cvt_kernel<<<1728, 256, 0, stream>>>(qkv_w, wqkvb, 2304 * 768 / 4);
  cvt_kernel<<<576, 256, 0, stream>>>(proj_w, wprojb, 768 * 768 / 4);
  cvt_rel<<<32, 256, 0, stream>>>(rph, rpw, rphb, rpwb);

  gemm_qkv<<<64 * 18, 256, 0, stream>>>(xb, wqkvb, qkv_b, qb, kb, vtb);

  attn_kernel<<<96 * 16, 256, 0, stream>>>(qb, kb, vtb, rphb, rpwb, ao);

  gemm_proj<<<64 * 6, 256, 0, stream>>>(ao, wprojb, proj_b, out);
}

// Round 3
// 186.656 us; speedup vs baseline: 1.9846x; 1.1316x over previous
//
#include <hip/hip_runtime.h>

typedef unsigned short u16;
typedef __bf16 bf16x8 __attribute__((ext_vector_type(8)));
typedef float f32x4 __attribute__((ext_vector_type(4)));

#define NHEAD 12
#define LQ 1024
#define HDIM 64
#define DIMM 768

__device__ __forceinline__ u16 f2b(float f) {
  unsigned u = __float_as_uint(f);
  u += 0x7fffu + ((u >> 16) & 1u);   // RNE; inputs are finite
  return (u16)(u >> 16);
}
__device__ __forceinline__ float b2f(u16 v) {
  return __uint_as_float(((unsigned)v) << 16);
}
__device__ __forceinline__ unsigned cvt_pk(float lo, float hi) {
  unsigned r;
  asm("v_cvt_pk_bf16_f32 %0, %1, %2" : "=v"(r) : "v"(lo), "v"(hi));
  return r;
}
__device__ __forceinline__ void async16(const void* g, void* l) {
  __builtin_amdgcn_global_load_lds(
      (const __attribute__((address_space(1))) void*)g,
      (__attribute__((address_space(3))) void*)l, 16, 0, 0);
}

// ---------------- f32 -> bf16 convert ----------------
__global__ __launch_bounds__(256) void cvt_kernel(const float* __restrict__ in,
                                                  u16* __restrict__ out, int n4) {
  int i = blockIdx.x * 256 + threadIdx.x;
  if (i >= n4) return;
  const float4 v = reinterpret_cast<const float4*>(in)[i];
  ushort4 o;
  o.x = f2b(v.x); o.y = f2b(v.y); o.z = f2b(v.z); o.w = f2b(v.w);
  reinterpret_cast<ushort4*>(out)[i] = o;
}

// rel tables -> padded bf16 [64][64] (row 63 zero, never indexed)
__global__ __launch_bounds__(256) void cvt_rel(const float* __restrict__ rph,
                                               const float* __restrict__ rpw,
                                               u16* __restrict__ rphb,
                                               u16* __restrict__ rpwb) {
  int i = blockIdx.x * 256 + threadIdx.x;   // 0..8191
  int tab = i >> 12, idx = i & 4095;
  int m = idx >> 6, d = idx & 63;
  const float* src = tab ? rpw : rph;
  u16* dst = tab ? rpwb : rphb;
  dst[idx] = (m < 63) ? f2b(src[m * HDIM + d]) : (u16)0;
}

// ---------------- QKV GEMM: C = A(8192x768) * Bt(2304x768)^T + bias ----------------
// scatter epilogue -> q[bh][l][d], k[bh][l][d], vT[bh][d][l]  (bf16)
__global__ __launch_bounds__(256) void gemm_qkv(const u16* __restrict__ A,
                                                const u16* __restrict__ Bt,
                                                const float* __restrict__ bias,
                                                u16* __restrict__ qb,
                                                u16* __restrict__ kb,
                                                u16* __restrict__ vtb) {
  __shared__ u16 la[128 * 32];
  __shared__ u16 lb[128 * 32];
  const int K = DIMM;
  int t = threadIdx.x;
  int lane = t & 63, wv = t >> 6;
  int l15 = lane & 15, l4 = lane >> 4;
  int bm = blockIdx.x / 18, bn = blockIdx.x % 18;
  int m0 = bm * 128, n0 = bn * 128;
  int wm = (wv >> 1) * 64, wn = (wv & 1) * 64;

  f32x4 acc[4][4];
  #pragma unroll
  for (int i = 0; i < 4; ++i)
    #pragma unroll
    for (int j = 0; j < 4; ++j) acc[i][j] = {0.f, 0.f, 0.f, 0.f};

  for (int k0 = 0; k0 < K; k0 += 32) {
    __syncthreads();
    #pragma unroll
    for (int i = 0; i < 2; ++i) {
      int c = i * 256 + t;
      int row = c >> 2, co = c & 3;
      async16(A + (m0 + row) * K + k0 + co * 8, (char*)la + c * 16);
      async16(Bt + (n0 + row) * K + k0 + co * 8, (char*)lb + c * 16);
    }
    __syncthreads();
    bf16x8 af[4], bfr[4];
    #pragma unroll
    for (int mi = 0; mi < 4; ++mi)
      af[mi] = *reinterpret_cast<const bf16x8*>(&la[(wm + mi * 16 + l15) * 32 + l4 * 8]);
    #pragma unroll
    for (int nj = 0; nj < 4; ++nj)
      bfr[nj] = *reinterpret_cast<const bf16x8*>(&lb[(wn + nj * 16 + l15) * 32 + l4 * 8]);
    #pragma unroll
    for (int mi = 0; mi < 4; ++mi)
      #pragma unroll
      for (int nj = 0; nj < 4; ++nj)
        acc[mi][nj] = __builtin_amdgcn_mfma_f32_16x16x32_bf16(af[mi], bfr[nj], acc[mi][nj], 0, 0, 0);
  }

  int part = (n0 >> 7) / 6;  // 0:q 1:k 2:v (768 = 6 tiles of 128)
  #pragma unroll
  for (int nj = 0; nj < 4; ++nj) {
    int n = n0 + wn + nj * 16 + l15;
    float bv = bias[n];
    int d = n & 63;
    int head = (n >> 6) % NHEAD;
    #pragma unroll
    for (int mi = 0; mi < 4; ++mi) {
      #pragma unroll
      for (int r = 0; r < 4; ++r) {
        int m = m0 + wm + mi * 16 + l4 * 4 + r;
        int b = m >> 10, li = m & 1023;
        int bh = b * NHEAD + head;
        u16 o = f2b(acc[mi][nj][r] + bv);
        if (part == 0)      qb[(bh * LQ + li) * HDIM + d] = o;
        else if (part == 1) kb[(bh * LQ + li) * HDIM + d] = o;
        else                vtb[(bh * HDIM + d) * LQ + li] = o;
      }
    }
  }
}

// ---------------- flash attention with fused decomposed rel-pos bias ----------------
// block: 4 waves, QBLK=64 (wave -> 16 rows), KV chunks of 64
// SWAPPED operands: mfma(K,Q) / mfma(V,P) so each lane owns one q-row's stats
// bias via T-tables: Th[l][m] = q[l].rph[m]; score bias = Th[l][hq-k1+31] + Tw[l][wq-k2+31]
__global__ __launch_bounds__(256) void attn_kernel(const u16* __restrict__ qb,
                                                   const u16* __restrict__ kb,
                                                   const u16* __restrict__ vtb,
                                                   const u16* __restrict__ rphb,
                                                   const u16* __restrict__ rpwb,
                                                   u16* __restrict__ ao) {
  __shared__ u16 lds_k[64 * 64];       // [key][d], source-swizzled
  __shared__ u16 lds_v[64 * 64];       // [d][key], source-swizzled
  __shared__ u16 lds_th[64 * 72];      // T-tables, bf16, padded stride 72
  __shared__ u16 lds_tw[64 * 72];
  __shared__ u16 lds_p[4][16 * 72];    // per-wave P tile [qrow][key], padded row 72

  int bid = blockIdx.x;
  int bh = bid >> 4;
  int q0 = (bid & 15) * 64;
  int t = threadIdx.x;
  int wv = t >> 6, lane = t & 63;
  int l15 = lane & 15, l4 = lane >> 4;

  // Q fragments (2 x K=32) straight from global
  bf16x8 qf[2];
  {
    const u16* qsrc = qb + (bh * LQ + q0 + wv * 16 + l15) * HDIM + l4 * 8;
    qf[0] = *reinterpret_cast<const bf16x8*>(qsrc);
    qf[1] = *reinterpret_cast<const bf16x8*>(qsrc + 32);
  }

  // compute T-tables via MFMA: wave wv owns rows [wv*16, wv*16+16) (wave-private, no barrier)
  #pragma unroll
  for (int c = 0; c < 4; ++c) {
    f32x4 th = {0.f, 0.f, 0.f, 0.f}, tw = {0.f, 0.f, 0.f, 0.f};
    #pragma unroll
    for (int ks2 = 0; ks2 < 2; ++ks2) {
      bf16x8 bhf = *reinterpret_cast<const bf16x8*>(&rphb[(c * 16 + l15) * HDIM + ks2 * 32 + l4 * 8]);
      bf16x8 bwf = *reinterpret_cast<const bf16x8*>(&rpwb[(c * 16 + l15) * HDIM + ks2 * 32 + l4 * 8]);
      th = __builtin_amdgcn_mfma_f32_16x16x32_bf16(qf[ks2], bhf, th, 0, 0, 0);
      tw = __builtin_amdgcn_mfma_f32_16x16x32_bf16(qf[ks2], bwf, tw, 0, 0, 0);
    }
    #pragma unroll
    for (int r = 0; r < 4; ++r) {
      int row = wv * 16 + l4 * 4 + r;
      lds_th[row * 72 + c * 16 + l15] = f2b(th[r]);
      lds_tw[row * 72 + c * 16 + l15] = f2b(tw[r]);
    }
  }

  // per-lane row constants (lane owns q-row l15 of its wave's 16 rows)
  int gq = q0 + wv * 16 + l15;
  int hq = gq >> 5, wq = gq & 31;
  int lrow = wv * 16 + l15;
  const u16* thp = &lds_th[lrow * 72 + hq + 31];   // [-k1]
  const u16* twp = &lds_tw[lrow * 72 + wq + 31];   // [-k2]

  float m_run = -1e30f, l_run = 0.f;
  f32x4 acc_o[4];
  #pragma unroll
  for (int dj = 0; dj < 4; ++dj) acc_o[dj] = {0.f, 0.f, 0.f, 0.f};

  u16* pl = &lds_p[wv][0];

  for (int kv0 = 0; kv0 < LQ; kv0 += 64) {
    __syncthreads();   // previous chunk's LDS reads done
    {
      const u16* ks = kb + (bh * LQ + kv0) * HDIM;
      const u16* vs = vtb + bh * HDIM * LQ + kv0;
      #pragma unroll
      for (int i = 0; i < 2; ++i) {
        int c = i * 256 + t;
        int row = c >> 3, co = c & 7;
        int g = co ^ (row & 7);          // source swizzle; LDS stays linear
        async16(ks + row * HDIM + g * 8, (char*)lds_k + c * 16);
        async16(vs + row * LQ + g * 8, (char*)lds_v + c * 16);
      }
    }
    __syncthreads();

    // QK^T swapped: C[col=qrow=l15][row=key]; lane -> keys kv0 + nj*16 + l4*4 + r
    f32x4 sc[4];
    #pragma unroll
    for (int nj = 0; nj < 4; ++nj) {
      f32x4 a = {0.f, 0.f, 0.f, 0.f};
      #pragma unroll
      for (int ks2 = 0; ks2 < 2; ++ks2) {
        int co = (ks2 * 4 + l4) ^ (l15 & 7);
        bf16x8 kf = *reinterpret_cast<const bf16x8*>(&lds_k[(nj * 16 + l15) * 64 + co * 8]);
        a = __builtin_amdgcn_mfma_f32_16x16x32_bf16(kf, qf[ks2], a, 0, 0, 0);
      }
      sc[nj] = a;
    }

    // scores + bias (all 16 belong to q-row l15)
    int kv5 = kv0 >> 5;
    float th0 = b2f(thp[-kv5]);        // k1 = kv5   (nj 0,1)
    float th1 = b2f(thp[-kv5 - 1]);    // k1 = kv5+1 (nj 2,3)
    float p[4][4];
    float cmax = -1e30f;
    #pragma unroll
    for (int nj = 0; nj < 4; ++nj) {
      float thv = (nj < 2) ? th0 : th1;
      int kb2 = (nj & 1) * 16 + l4 * 4;       // k2 = kb2 + r
      #pragma unroll
      for (int r = 0; r < 4; ++r) {
        float s = fmaf(sc[nj][r], 0.125f, thv) + b2f(twp[-(kb2 + r)]);
        p[nj][r] = s;
        cmax = fmaxf(cmax, s);
      }
    }
    cmax = fmaxf(cmax, __shfl_xor(cmax, 16));
    cmax = fmaxf(cmax, __shfl_xor(cmax, 32));

    // defer-max (T13): rescale only when some row grew by > 8
    if (!__all(cmax <= m_run + 8.0f)) {
      float mn = fmaxf(m_run, cmax);
      float scl = __expf(m_run - mn);
      m_run = mn;
      l_run *= scl;
      #pragma unroll
      for (int dj = 0; dj < 4; ++dj)
        #pragma unroll
        for (int r = 0; r < 4; ++r) acc_o[dj][r] *= scl;
    }

    float psum = 0.f;
    #pragma unroll
    for (int nj = 0; nj < 4; ++nj)
      #pragma unroll
      for (int r = 0; r < 4; ++r) {
        p[nj][r] = __expf(p[nj][r] - m_run);
        psum += p[nj][r];
      }
    psum += __shfl_xor(psum, 16);
    psum += __shfl_xor(psum, 32);
    l_run += psum;

    // P -> LDS packed (4x ds_write_b64), layout pl[qrow=l15][key]
    #pragma unroll
    for (int nj = 0; nj < 4; ++nj) {
      uint2 pk;
      pk.x = cvt_pk(p[nj][0], p[nj][1]);
      pk.y = cvt_pk(p[nj][2], p[nj][3]);
      *reinterpret_cast<uint2*>(&pl[l15 * 72 + nj * 16 + l4 * 4]) = pk;
    }

    bf16x8 pf[2];
    pf[0] = *reinterpret_cast<const bf16x8*>(&pl[l15 * 72 + l4 * 8]);
    pf[1] = *reinterpret_cast<const bf16x8*>(&pl[l15 * 72 + 32 + l4 * 8]);

    // PV swapped: acc_o[dj] holds O^T[d = dj*16+4*l4+r][qrow = l15]
    #pragma unroll
    for (int dj = 0; dj < 4; ++dj) {
      int d = dj * 16 + l15;
      #pragma unroll
      for (int ks2 = 0; ks2 < 2; ++ks2) {
        int co = (ks2 * 4 + l4) ^ (l15 & 7);
        bf16x8 vf = *reinterpret_cast<const bf16x8*>(&lds_v[d * 64 + co * 8]);
        acc_o[dj] = __builtin_amdgcn_mfma_f32_16x16x32_bf16(vf, pf[ks2], acc_o[dj], 0, 0, 0);
      }
    }
  }

  // epilogue: normalize, packed 8B stores; lane owns q-row gq, d = dj*16 + l4*4 + r
  int b = bh / NHEAD, head = bh % NHEAD;
  float inv = 1.f / l_run;
  u16* orow = ao + (b * LQ + gq) * DIMM + head * HDIM;
  #pragma unroll
  for (int dj = 0; dj < 4; ++dj) {
    uint2 pk;
    pk.x = cvt_pk(acc_o[dj][0] * inv, acc_o[dj][1] * inv);
    pk.y = cvt_pk(acc_o[dj][2] * inv, acc_o[dj][3] * inv);
    *reinterpret_cast<uint2*>(&orow[dj * 16 + l4 * 4]) = pk;
  }
}

// ---------------- proj GEMM: out = A(8192x768) * Bt(768x768)^T + bias (f32 out) ----------------
__global__ __launch_bounds__(256) void gemm_proj(const u16* __restrict__ A,
                                                 const u16* __restrict__ Bt,
                                                 const float* __restrict__ bias,
                                                 float* __restrict__ out) {
  __shared__ u16 la[128 * 32];
  __shared__ u16 lb[128 * 32];
  const int K = DIMM;
  int t = threadIdx.x;
  int lane = t & 63, wv = t >> 6;
  int l15 = lane & 15, l4 = lane >> 4;
  int bm = blockIdx.x / 6, bn = blockIdx.x % 6;
  int m0 = bm * 128, n0 = bn * 128;
  int wm = (wv >> 1) * 64, wn = (wv & 1) * 64;

  f32x4 acc[4][4];
  #pragma unroll
  for (int i = 0; i < 4; ++i)
    #pragma unroll
    for (int j = 0; j < 4; ++j) acc[i][j] = {0.f, 0.f, 0.f, 0.f};

  for (int k0 = 0; k0 < K; k0 += 32) {
    __syncthreads();
    #pragma unroll
    for (int i = 0; i < 2; ++i) {
      int c = i * 256 + t;
      int row = c >> 2, co = c & 3;
      async16(A + (m0 + row) * K + k0 + co * 8, (char*)la + c * 16);
      async16(Bt + (n0 + row) * K + k0 + co * 8, (char*)lb + c * 16);
    }
    __syncthreads();
    bf16x8 af[4], bfr[4];
    #pragma unroll
    for (int mi = 0; mi < 4; ++mi)
      af[mi] = *reinterpret_cast<const bf16x8*>(&la[(wm + mi * 16 + l15) * 32 + l4 * 8]);
    #pragma unroll
    for (int nj = 0; nj < 4; ++nj)
      bfr[nj] = *reinterpret_cast<const bf16x8*>(&lb[(wn + nj * 16 + l15) * 32 + l4 * 8]);
    #pragma unroll
    for (int mi = 0; mi < 4; ++mi)
      #pragma unroll
      for (int nj = 0; nj < 4; ++nj)
        acc[mi][nj] = __builtin_amdgcn_mfma_f32_16x16x32_bf16(af[mi], bfr[nj], acc[mi][nj], 0, 0, 0);
  }

  #pragma unroll
  for (int nj = 0; nj < 4; ++nj) {
    int n = n0 + wn + nj * 16 + l15;
    float bv = bias[n];
    #pragma unroll
    for (int mi = 0; mi < 4; ++mi) {
      #pragma unroll
      for (int r = 0; r < 4; ++r) {
        int m = m0 + wm + mi * 16 + l4 * 4 + r;
        out[m * DIMM + n] = acc[mi][nj][r] + bv;
      }
    }
  }
}

extern "C" void kernel_launch(void* const* d_in, const int* in_sizes, int n_in,
                              void* d_out, int out_size, void* d_ws, size_t ws_size,
                              hipStream_t stream) {
  const float* x      = (const float*)d_in[0];
  const float* qkv_w  = (const float*)d_in[1];
  const float* qkv_b  = (const float*)d_in[2];
  const float* proj_w = (const float*)d_in[3];
  const float* proj_b = (const float*)d_in[4];
  const float* rph    = (const float*)d_in[5];
  const float* rpw    = (const float*)d_in[6];
  float* out = (float*)d_out;
  char* ws = (char*)d_ws;

  // workspace layout (ao aliases xb)
  u16*   xb     = (u16*)(ws + 0);          // 8192*768 bf16 (12.58 MB)
  u16*   wqkvb  = (u16*)(ws + 12582912);   // 2304*768
  u16*   wprojb = (u16*)(ws + 16121856);   // 768*768
  u16*   qb     = (u16*)(ws + 17301504);   // 96*1024*64
  u16*   kb     = (u16*)(ws + 29884416);
  u16*   vtb    = (u16*)(ws + 42467328);   // transposed V [bh][d][l]
  u16*   rphb   = (u16*)(ws + 55050240);   // padded bf16 [64][64]
  u16*   rpwb   = (u16*)(ws + 55058432);
  u16*   ao     = xb;                      // reuse after QKV GEMM consumed xb

  cvt_kernel<<<6144, 256, 0, stream>>>(x, xb, 8192 * 768 / 4);
  cvt_kernel<<<1728, 256, 0, stream>>>(qkv_w, wqkvb, 2304 * 768 / 4);
  cvt_kernel<<<576, 256, 0, stream>>>(proj_w, wprojb, 768 * 768 / 4);
  cvt_rel<<<32, 256, 0, stream>>>(rph, rpw, rphb, rpwb);

  gemm_qkv<<<64 * 18, 256, 0, stream>>>(xb, wqkvb, qkv_b, qb, kb, vtb);

  attn_kernel<<<96 * 16, 256, 0, stream>>>(qb, kb, vtb, rphb, rpwb, ao);

  gemm_proj<<<64 * 6, 256, 0, stream>>>(ao, wprojb, proj_b, out);
}